// Round 11
// baseline (485.339 us; speedup 1.0000x reference)
//
#include <hip/hip_runtime.h>
#include <hip/hip_bf16.h>
#include <math.h>

// Problem constants
#define B_    2
#define FIN_  256
#define LIN_  250
#define F_    128      // F_OUT
#define K_    16       // KSIZE
#define ST_   8        // STRIDE
#define L_    2008     // L_OUT
#define DI_   256      // D_INNER
#define DS_   16       // D_STATE
#define RK_   8        // DT_RANK
#define CV_   4        // D_CONV
#define NBLK_ 2
#define NC_   64       // scan chunks (trailing chunk empty: identity summary)
#define CL_   32       // chunk length
#define RL_   ((size_t)B_ * L_)   // rows per direction = 4016 (= 502*8 exactly)

__device__ __forceinline__ float silu_f(float x) {
    return x / (1.f + __expf(-x));
}
__device__ __forceinline__ float softplus_f(float x) {
    return (x > 20.f) ? x : log1pf(__expf(x));
}
__device__ __forceinline__ float dot4(float4 a, float4 b) {
    return a.x * b.x + a.y * b.y + a.z * b.z + a.w * b.w;
}

// ---------------------------------------------------------------------------
// prep: packed transposed weights, each as [c/4][out][4] so a thread's 4-c
// weight bundle is ONE coalesced dwordx4.
// ---------------------------------------------------------------------------
#define PREP_N (524288 + 32768 + 262144 + 262144 + 65536)
__global__ void prep_k(const float* __restrict__ convT_w, const float* __restrict__ fuse_w,
                       const float* __restrict__ in_proj, const float* __restrict__ out_proj,
                       const float* __restrict__ x_proj,
                       float* __restrict__ W2p, float* __restrict__ fwTp,
                       float* __restrict__ ipTp, float* __restrict__ opTp,
                       float* __restrict__ xpTp) {
    size_t g = (size_t)blockIdx.x * 256 + threadIdx.x;
    if (g >= PREP_N) return;
    if (g < 524288) {
        int ccq = g >> 12, rr = g & 4095;
        int po = rr >> 2, i = rr & 3;
        int cc = ccq * 4 + i;
        int p = po >> 7, o = po & 127;
        int c = cc & 255, k = (cc < 256) ? p : p + 8;
        W2p[g] = convT_w[(size_t)c * 2048 + o * 16 + k];
        return;
    }
    g -= 524288;
    if (g < 32768) {
        int cq = g >> 9, rr = g & 511;
        int o = rr >> 2, i = rr & 3;
        fwTp[g] = fuse_w[(size_t)o * 256 + cq * 4 + i];
        return;
    }
    g -= 32768;
    if (g < 262144) {
        int db = g >> 16, r = g & 65535;
        int cq = r >> 11, rr = r & 2047;
        int e = rr >> 2, i = rr & 3;
        ipTp[g] = in_proj[(size_t)db * 65536 + e * 128 + cq * 4 + i];
        return;
    }
    g -= 262144;
    if (g < 262144) {
        int db = g >> 15, r = g & 32767;
        int cq = r >> 9, rr = r & 511;
        int o = rr >> 2, i = rr & 3;
        opTp[g] = out_proj[(size_t)db * 32768 + o * 256 + cq * 4 + i];
        return;
    }
    g -= 262144;
    {
        int db = g >> 14, r = g & 16383;
        int cq = r >> 8, rr = r & 255;
        int e = rr >> 2, i = rr & 3;
        xpTp[g] = (e < 40) ? x_proj[(size_t)db * 10240 + e * 256 + cq * 4 + i] : 0.f;
    }
}

// ---------------------------------------------------------------------------
// convT+silu GEMM, 2 outputs/thread. grid (63 jt of 4, 2 nt, B), block 256.
// ---------------------------------------------------------------------------
__global__ void __launch_bounds__(256) convt5_k(
        const float* __restrict__ x, const float* __restrict__ W2p,
        const float* __restrict__ bias, float* __restrict__ hT) {
    int j0 = blockIdx.x * 4, nt = blockIdx.y, b = blockIdx.z;
    int po = nt * 512 + threadIdx.x;
    int p = po >> 7, o = po & 127;

    __shared__ float xr[5][264];   // rows j0-1 .. j0+3

    for (int idx = threadIdx.x; idx < 5 * 256; idx += 256) {
        int i = idx >> 8, c = idx & 255;
        int j = j0 - 1 + i;
        xr[i][c] = (j >= 0 && j < LIN_) ? x[((size_t)b * FIN_ + c) * LIN_ + j] : 0.f;
    }
    __syncthreads();

    float acca[4] = {0.f, 0.f, 0.f, 0.f};
    float accb[4] = {0.f, 0.f, 0.f, 0.f};
    const float4* W4 = (const float4*)W2p;

    for (int ccq = 0; ccq < 64; ++ccq) {
        float4 wa1 = W4[(size_t)ccq * 1024 + po];
        float4 wb1 = W4[(size_t)ccq * 1024 + po + 256];
        float4 wa2 = W4[(size_t)(ccq + 64) * 1024 + po];
        float4 wb2 = W4[(size_t)(ccq + 64) * 1024 + po + 256];
        float4 xv[5];
        #pragma unroll
        for (int i = 0; i < 5; ++i) xv[i] = *(const float4*)&xr[i][ccq * 4];
        #pragma unroll
        for (int jj = 0; jj < 4; ++jj) {
            acca[jj] += dot4(xv[jj + 1], wa1) + dot4(xv[jj], wa2);
            accb[jj] += dot4(xv[jj + 1], wb1) + dot4(xv[jj], wb2);
        }
    }
    float bo = bias[o];
    #pragma unroll
    for (int jj = 0; jj < 4; ++jj) {
        int j = j0 + jj;
        if (j <= 250) {
            hT[((size_t)b * L_ + 8 * j + p) * F_ + o]     = silu_f(acca[jj] + bo);
            hT[((size_t)b * L_ + 8 * j + p + 2) * F_ + o] = silu_f(accb[jj] + bo);
        }
    }
}

// ---------------------------------------------------------------------------
// fuse = silu(fuse_w @ [skip; h] + b); 2 outs/thread; xs fwd + flipped bwd.
// grid (251 l-tiles of 8, B), block 256
// ---------------------------------------------------------------------------
__global__ void __launch_bounds__(256) fuse5_k(
        const float* __restrict__ skip, const float* __restrict__ hT,
        const float* __restrict__ fwTp, const float* __restrict__ fb,
        float* __restrict__ xs) {
    int l0 = blockIdx.x * 8, b = blockIdx.y;
    int tid = threadIdx.x;

    __shared__ float ss[8][264];

    for (int idx = tid; idx < 128 * 8; idx += 256) {   // skip part (c<128)
        int c = idx >> 3, ll = idx & 7;
        ss[ll][c] = skip[((size_t)b * F_ + c) * L_ + l0 + ll];
    }
    for (int idx = tid; idx < 8 * 128; idx += 256) {   // h part (c>=128)
        int ll = idx >> 7, c = idx & 127;
        ss[ll][128 + c] = hT[((size_t)b * L_ + l0 + ll) * F_ + c];
    }
    __syncthreads();

    int o2 = tid & 63, rg = tid >> 6;
    float acca[2] = {0.f, 0.f}, accb[2] = {0.f, 0.f};
    const float4* W4 = (const float4*)fwTp;

    for (int cq = 0; cq < 64; ++cq) {
        float4 wa = W4[cq * 128 + o2];
        float4 wb = W4[cq * 128 + o2 + 64];
        #pragma unroll
        for (int rr = 0; rr < 2; ++rr) {
            float4 s = *(const float4*)&ss[rg * 2 + rr][cq * 4];
            acca[rr] += dot4(s, wa);
            accb[rr] += dot4(s, wb);
        }
    }
    float ba = fb[o2], bb = fb[o2 + 64];
    #pragma unroll
    for (int rr = 0; rr < 2; ++rr) {
        int l = l0 + rg * 2 + rr;
        float va = silu_f(acca[rr] + ba);
        float vb = silu_f(accb[rr] + bb);
        size_t rf = ((size_t)b * L_ + l) * F_;
        size_t rb = (RL_ + (size_t)b * L_ + (L_ - 1 - l)) * F_;
        xs[rf + o2] = va;       xs[rf + o2 + 64] = vb;
        xs[rb + o2] = va;       xs[rb + o2 + 64] = vb;
    }
}

// ---------------------------------------------------------------------------
// lndw: rows-tile 8. LN(11 rows w/ halo) -> in_proj BOTH halves in ONE loop
// (each us read feeds 2 outputs) -> depthwise conv in regs -> silu -> XC+xcs;
// z -> XZz; then x_proj(40)+dt_proj(256)+softplus. grid (502, 2), block 256.
// [Structure unchanged from r9/r10 (control); added pointer-bump + unroll
//  pragmas on the weight-stream loops to help load pipelining.]
// ---------------------------------------------------------------------------
__global__ void __launch_bounds__(256) lndw_k(
        const float* __restrict__ X, const float* __restrict__ nw,
        const float* __restrict__ nb_, const float* __restrict__ ipTp,
        const float* __restrict__ cw, const float* __restrict__ cb,
        const float* __restrict__ xpTp, const float* __restrict__ dtw,
        const float* __restrict__ dtb,
        float* __restrict__ XC, float* __restrict__ XZz,
        float* __restrict__ BCM, float* __restrict__ DELTA, int blk) {
    int rt = blockIdx.x, d = blockIdx.y;
    size_t rbase = (size_t)rt * 8;
    int tid = threadIdx.x, lane = tid & 63, wid = tid >> 6;
    int db = d * NBLK_ + blk;
    size_t dRL = (size_t)d * RL_;

    __shared__ float us[11][132];
    __shared__ float xcs[8][264];
    __shared__ float dts[8][8];

    // LN for staged rows rbase-3 .. rbase+7
    int wi0 = db * F_;
    for (int r = wid; r < 11; r += 4) {
        long grow = (long)rbase - 3 + r;
        float2 v = make_float2(0.f, 0.f);
        if (grow >= 0)
            v = *(const float2*)(X + (dRL + (size_t)grow) * F_ + lane * 2);
        float s1 = v.x + v.y, s2 = v.x * v.x + v.y * v.y;
        for (int off = 32; off; off >>= 1) {
            s1 += __shfl_xor(s1, off);
            s2 += __shfl_xor(s2, off);
        }
        float mu = s1 * (1.f / F_);
        float var = s2 * (1.f / F_) - mu * mu;
        float rstd = rsqrtf(var + 1e-5f);
        int c2 = lane * 2;
        us[r][c2]     = (v.x - mu) * rstd * nw[wi0 + c2]     + nb_[wi0 + c2];
        us[r][c2 + 1] = (v.y - mu) * rstd * nw[wi0 + c2 + 1] + nb_[wi0 + c2 + 1];
    }
    __syncthreads();

    int o = tid;   // channel index, 0..255

    // in_proj x-half (11 rows) AND z-half (8 rows) sharing each us read
    float accx[11], accz[8];
    #pragma unroll
    for (int i = 0; i < 11; ++i) accx[i] = 0.f;
    #pragma unroll
    for (int i = 0; i < 8; ++i) accz[i] = 0.f;
    {
        const float4* wpx = (const float4*)(ipTp + (size_t)db * 65536) + o;
        const float4* wpz = wpx + 256;
        #pragma unroll 2
        for (int cq = 0; cq < 32; ++cq) {
            float4 wx = *wpx; wpx += 512;
            float4 wz = *wpz; wpz += 512;
            #pragma unroll
            for (int r = 0; r < 11; ++r) {
                float4 u = *(const float4*)&us[r][cq * 4];
                accx[r] += dot4(u, wx);
                if (r >= 3) accz[r - 3] += dot4(u, wz);
            }
        }
    }

    // depthwise conv + silu, in registers (thread owns channel o)
    {
        int wi = db * DI_ + o;
        float cw0 = cw[(size_t)wi * CV_ + 0], cw1 = cw[(size_t)wi * CV_ + 1];
        float cw2 = cw[(size_t)wi * CV_ + 2], cw3 = cw[(size_t)wi * CV_ + 3];
        float bias = cb[wi];
        #pragma unroll
        for (int r8 = 0; r8 < 8; ++r8) {
            size_t row = rbase + r8;
            int b_r = (row >= L_) ? 1 : 0;
            int l_r = (int)row - b_r * L_;
            int s = r8 + 3;
            float a = bias + accx[s] * cw3;
            if (l_r - 1 >= 0) a += accx[s - 1] * cw2;
            if (l_r - 2 >= 0) a += accx[s - 2] * cw1;
            if (l_r - 3 >= 0) a += accx[s - 3] * cw0;
            float v = silu_f(a);
            xcs[r8][o] = v;
            XC[(dRL + row) * DI_ + o] = v;
            XZz[(dRL + row) * DI_ + o] = accz[r8];
        }
    }
    __syncthreads();

    // x_proj: e = tid&63 (e<40 active), rg = tid>>6 covers 2 rows each
    {
        int e = tid & 63, rg = tid >> 6;
        float acc2[2] = {0.f, 0.f};
        const float4* wp = (const float4*)(xpTp + (size_t)db * 16384) + e;
        #pragma unroll 4
        for (int cq = 0; cq < 64; ++cq) {
            float4 w = *wp; wp += 64;
            #pragma unroll
            for (int rr = 0; rr < 2; ++rr)
                acc2[rr] += dot4(*(const float4*)&xcs[rg * 2 + rr][cq * 4], w);
        }
        if (e < RK_) {
            #pragma unroll
            for (int rr = 0; rr < 2; ++rr) dts[rg * 2 + rr][e] = acc2[rr];
        } else if (e < RK_ + 2 * DS_) {
            #pragma unroll
            for (int rr = 0; rr < 2; ++rr) {
                size_t row = rbase + rg * 2 + rr;
                BCM[(dRL + row) * 32 + (e - RK_)] = acc2[rr];
            }
        }
    }
    __syncthreads();

    // dt_proj + softplus
    {
        int wi = db * DI_ + o;
        float dwv[RK_];
        #pragma unroll
        for (int k = 0; k < RK_; ++k) dwv[k] = dtw[(size_t)wi * RK_ + k];
        float bias = dtb[wi];
        #pragma unroll
        for (int rr = 0; rr < 8; ++rr) {
            size_t row = rbase + rr;
            float a = bias;
            #pragma unroll
            for (int k = 0; k < RK_; ++k) a += dts[rr][k] * dwv[k];
            DELTA[(dRL + row) * DI_ + o] = softplus_f(a);
        }
    }
}

// ---------------------------------------------------------------------------
// scanA: LDS-staged chunk-local scan (CL=32). The h-recurrence runs SHFL-FREE
// (py/cum kept in registers, statically indexed); the 32 4-level shfl reduces
// run afterwards, mutually independent (issue-bound, off the critical path).
// Emits local y (with D*u folded), cum(dt) (overwrites DELTA), hpart, dtsum.
// grid (32 chgrp, NC_, 2), block 256 = 16 chl x 16 n
// ---------------------------------------------------------------------------
__global__ void __launch_bounds__(256) scanA_k(
        float* __restrict__ DELTA, const float* __restrict__ XC,
        const float* __restrict__ BCM, const float* __restrict__ A_log,
        const float* __restrict__ Dsk,
        float* __restrict__ Y, float* __restrict__ hpart,
        float* __restrict__ dsum, int blk) {
    int d = blockIdx.z, cnk = blockIdx.y;
    int chunit0 = blockIdx.x * 16;
    int chl = threadIdx.x >> 4, n = threadIdx.x & 15;
    int b = chunit0 >> 8, ch0 = chunit0 & 255;
    int ch = ch0 + chl;
    int t0 = cnk * CL_;
    int nt = L_ - t0; if (nt > CL_) nt = CL_;   // may be <= 0 (empty chunk)

    __shared__ float dt_s[CL_][16];
    __shared__ float u_s[CL_][16];
    __shared__ float bc_s[CL_][32];

    size_t rowbase = (size_t)d * RL_ + (size_t)b * L_ + t0;
    for (int idx = threadIdx.x; idx < CL_ * 16; idx += 256) {
        int t = idx >> 4, c = idx & 15;
        float dv = 0.f, uv = 0.f;
        if (t < nt) {
            dv = DELTA[(rowbase + t) * DI_ + ch0 + c];
            uv = XC[(rowbase + t) * DI_ + ch0 + c];
        }
        dt_s[t][c] = dv; u_s[t][c] = uv;
    }
    for (int idx = threadIdx.x; idx < CL_ * 32; idx += 256) {
        int t = idx >> 5, m = idx & 31;
        bc_s[t][m] = (t < nt) ? BCM[(rowbase + t) * 32 + m] : 0.f;
    }
    __syncthreads();

    int db = d * NBLK_ + blk;
    float A = -__expf(A_log[((size_t)db * DI_ + ch) * DS_ + n]);
    float h = 0.f, cum = 0.f;
    float py[CL_], cums[CL_];

    // serial h-chain, no cross-lane ops (zeros staged past nt keep h/cum exact)
    #pragma unroll
    for (int t = 0; t < CL_; ++t) {
        float dt = dt_s[t][chl];
        float u  = u_s[t][chl];
        float Bt = bc_s[t][n];
        float Ct = bc_s[t][16 + n];
        cum += dt;
        h = __expf(dt * A) * h + dt * u * Bt;
        py[t] = h * Ct;
        cums[t] = cum;
    }
    size_t cb = (size_t)(d * B_ + b) * NC_ + cnk;
    hpart[cb * (DI_ * DS_) + ch * DS_ + n] = h;
    if (n == 0) dsum[cb * DI_ + ch] = cum;

    // batched independent reduces + stores
    float Dch = Dsk[(size_t)db * DI_ + ch];
    #pragma unroll
    for (int t = 0; t < CL_; ++t) {
        if (t >= nt) break;            // uniform per wave (same chunk)
        float yp = py[t];
        yp += __shfl_xor(yp, 1);
        yp += __shfl_xor(yp, 2);
        yp += __shfl_xor(yp, 4);
        yp += __shfl_xor(yp, 8);
        if (n == 0) {
            Y[(rowbase + t) * DI_ + ch] = yp + Dch * u_s[t][chl];
            DELTA[(rowbase + t) * DI_ + ch] = cums[t];
        }
    }
}

// ---------------------------------------------------------------------------
// scanB: cross-chunk scan of summaries, LDS-staged. In-place on hpart.
// grid (32 chgrp of 8 ch, B, 2 dirs), block 256
// ---------------------------------------------------------------------------
__global__ void __launch_bounds__(256) scanB_k(
        float* __restrict__ hpart, const float* __restrict__ dsum,
        const float* __restrict__ A_log, int blk) {
    int chg = blockIdx.x, b = blockIdx.y, d = blockIdx.z;
    int ch0 = chg * 8;
    __shared__ float hs[NC_][8][16];   // 32 KB
    __shared__ float ds_s[NC_][8];     // 2 KB
    size_t cb0 = (size_t)(d * B_ + b) * NC_;

    for (int idx = threadIdx.x; idx < NC_ * 128; idx += 256) {
        int c = idx >> 7, r = idx & 127;
        hs[c][r >> 4][r & 15] =
            hpart[(cb0 + c) * (DI_ * DS_) + (size_t)(ch0 + (r >> 4)) * DS_ + (r & 15)];
    }
    for (int idx = threadIdx.x; idx < NC_ * 8; idx += 256) {
        int c = idx >> 3, r = idx & 7;
        ds_s[c][r] = dsum[(cb0 + c) * DI_ + ch0 + r];
    }
    __syncthreads();

    if (threadIdx.x < 128) {
        int chl = threadIdx.x >> 4, n = threadIdx.x & 15;
        float A = -__expf(A_log[((size_t)(d * NBLK_ + blk) * DI_ + ch0 + chl) * DS_ + n]);
        float h = 0.f;
        for (int c = 0; c < NC_; ++c) {
            float hc = hs[c][chl][n];
            hs[c][chl][n] = h;               // carry-in for chunk c
            h = __expf(A * ds_s[c][chl]) * h + hc;
        }
    }
    __syncthreads();

    for (int idx = threadIdx.x; idx < NC_ * 128; idx += 256) {
        int c = idx >> 7, r = idx & 127;
        hpart[(cb0 + c) * (DI_ * DS_) + (size_t)(ch0 + (r >> 4)) * DS_ + (r & 15)] =
            hs[c][r >> 4][r & 15];
    }
}

// ---------------------------------------------------------------------------
// gateC: correction + gate + out_proj GEMM (+ residual), rows-tile 8.
// (blk0 path — produces res1.) grid (502, 2), block 256.
// ---------------------------------------------------------------------------
__global__ void __launch_bounds__(256) gateC_k(
        const float* __restrict__ Y, const float* __restrict__ XZz,
        const float* __restrict__ DELTA /*=cum*/, const float* __restrict__ BCM,
        const float* __restrict__ A_log, const float* __restrict__ hcarry,
        const float* __restrict__ opTp, const float* __restrict__ resid_in,
        float* __restrict__ outp, int blk) {
    int rt = blockIdx.x, d = blockIdx.y;
    int tid = threadIdx.x;
    size_t rbase = (size_t)rt * 8;
    int db = d * NBLK_ + blk;
    size_t dRL = (size_t)d * RL_;

    __shared__ float yg[8][264];
    __shared__ float Cs[8][16];

    if (tid < 128) {
        int r = tid >> 4, n = tid & 15;
        Cs[r][n] = BCM[(dRL + rbase + r) * 32 + 16 + n];
    }
    __syncthreads();

    {
        int c = tid;   // channel
        float An[16];
        const float* Ab = A_log + ((size_t)db * DI_ + c) * DS_;
        #pragma unroll
        for (int n = 0; n < 16; ++n) An[n] = -__expf(Ab[n]);

        int b0 = (rbase >= L_) ? 1 : 0;
        int l0 = (int)rbase - b0 * L_;
        int ck0 = l0 >> 5;
        const float* hp0 = hcarry + ((size_t)(d * B_ + b0) * NC_ + ck0) * (DI_ * DS_) + (size_t)c * DS_;
        float K0[16];
        #pragma unroll
        for (int q = 0; q < 4; ++q) {
            float4 v0 = *(const float4*)(hp0 + q * 4);
            K0[4*q] = v0.x; K0[4*q+1] = v0.y; K0[4*q+2] = v0.z; K0[4*q+3] = v0.w;
        }

        #pragma unroll
        for (int r = 0; r < 8; ++r) {
            size_t ri = dRL + rbase + r;
            float cum = DELTA[ri * DI_ + c];
            float corr = 0.f;
            #pragma unroll
            for (int n = 0; n < 16; ++n)
                corr += Cs[r][n] * K0[n] * __expf(An[n] * cum);
            float yv = Y[ri * DI_ + c] + corr;
            float z  = XZz[ri * DI_ + c];
            yg[r][c] = yv * silu_f(z);
        }
    }
    __syncthreads();

    int o2 = tid & 63, rg = tid >> 6;
    float acca[2] = {0.f, 0.f};
    float accb[2] = {0.f, 0.f};
    const float4* W4 = (const float4*)(opTp + (size_t)db * 32768);

    for (int cq = 0; cq < 64; ++cq) {
        float4 wa = W4[cq * 128 + o2];
        float4 wb = W4[cq * 128 + o2 + 64];
        #pragma unroll
        for (int rr = 0; rr < 2; ++rr) {
            float4 u = *(const float4*)&yg[rg * 2 + rr][cq * 4];
            acca[rr] += dot4(u, wa);
            accb[rr] += dot4(u, wb);
        }
    }
    #pragma unroll
    for (int rr = 0; rr < 2; ++rr) {
        size_t ri = dRL + rbase + rg * 2 + rr;
        float va = acca[rr] + resid_in[ri * F_ + o2];
        float vb = accb[rr] + resid_in[ri * F_ + o2 + 64];
        outp[ri * F_ + o2]      = va;
        outp[ri * F_ + o2 + 64] = vb;
    }
}

// ---------------------------------------------------------------------------
// gateC2: blk1 final stage. One block handles the fwd tile (dir0, rows l0..)
// AND the matching flipped bwd tile (dir1, rows L-8-l0..), sums both (+res1)
// and writes out[b,o,l] directly. grid (502), block 256.
// ---------------------------------------------------------------------------
__global__ void __launch_bounds__(256) gateC2_k(
        const float* __restrict__ Y, const float* __restrict__ XZz,
        const float* __restrict__ DELTA /*=cum*/, const float* __restrict__ BCM,
        const float* __restrict__ A_log, const float* __restrict__ hcarry,
        const float* __restrict__ opTp, const float* __restrict__ res1,
        float* __restrict__ out) {
    int rt = blockIdx.x;                 // 0..501
    int b = rt / 251, l0 = (rt % 251) * 8;
    int tid = threadIdx.x;

    __shared__ float yg[8][264];
    __shared__ float og[8][132];
    __shared__ float Cs[2][8][16];

    {
        int dd = tid >> 7, r = (tid >> 4) & 7, n = tid & 15;
        int lb = dd ? (L_ - 8 - l0) : l0;
        size_t row = (size_t)dd * RL_ + (size_t)b * L_ + lb + r;
        Cs[dd][r][n] = BCM[row * 32 + 16 + n];
    }
    __syncthreads();

    for (int dd = 0; dd < 2; ++dd) {
        int lb = dd ? (L_ - 8 - l0) : l0;
        size_t rowbase = (size_t)dd * RL_ + (size_t)b * L_ + lb;
        int db = dd * NBLK_ + 1;

        {
            int c = tid;   // channel
            float An[16];
            const float* Ab = A_log + ((size_t)db * DI_ + c) * DS_;
            #pragma unroll
            for (int n = 0; n < 16; ++n) An[n] = -__expf(Ab[n]);

            int ck0 = lb >> 5;   // 8-aligned tile is chunk-contained
            const float* hp0 = hcarry + ((size_t)(dd * B_ + b) * NC_ + ck0) * (DI_ * DS_) + (size_t)c * DS_;
            float K0[16];
            #pragma unroll
            for (int q = 0; q < 4; ++q) {
                float4 v0 = *(const float4*)(hp0 + q * 4);
                K0[4*q] = v0.x; K0[4*q+1] = v0.y; K0[4*q+2] = v0.z; K0[4*q+3] = v0.w;
            }

            #pragma unroll
            for (int r = 0; r < 8; ++r) {
                size_t ri = rowbase + r;
                float cum = DELTA[ri * DI_ + c];
                float corr = 0.f;
                #pragma unroll
                for (int n = 0; n < 16; ++n)
                    corr += Cs[dd][r][n] * K0[n] * __expf(An[n] * cum);
                float yv = Y[ri * DI_ + c] + corr;
                float z  = XZz[ri * DI_ + c];
                yg[r][c] = yv * silu_f(z);
            }
        }
        __syncthreads();

        int o2 = tid & 63, rg = tid >> 6;
        float acca[2] = {0.f, 0.f};
        float accb[2] = {0.f, 0.f};
        const float4* W4 = (const float4*)(opTp + (size_t)db * 32768);

        for (int cq = 0; cq < 64; ++cq) {
            float4 wa = W4[cq * 128 + o2];
            float4 wb = W4[cq * 128 + o2 + 64];
            #pragma unroll
            for (int rr = 0; rr < 2; ++rr) {
                float4 u = *(const float4*)&yg[rg * 2 + rr][cq * 4];
                acca[rr] += dot4(u, wa);
                accb[rr] += dot4(u, wb);
            }
        }
        #pragma unroll
        for (int rr = 0; rr < 2; ++rr) {
            int ll = rg * 2 + rr;
            size_t ri = rowbase + ll;
            float va = acca[rr] + res1[ri * F_ + o2];
            float vb = accb[rr] + res1[ri * F_ + o2 + 64];
            if (dd == 0) {
                og[ll][o2]      = va;
                og[ll][o2 + 64] = vb;
            } else {
                og[7 - ll][o2]      += va;    // flip: out l = l0 + 7 - r
                og[7 - ll][o2 + 64] += vb;
            }
        }
        __syncthreads();   // protect yg reuse / og completion
    }

    for (int idx = tid; idx < 1024; idx += 256) {
        int o = idx >> 3, ll = idx & 7;
        out[((size_t)b * F_ + o) * L_ + l0 + ll] = og[ll][o];
    }
}

// ---------------------------------------------------------------------------
extern "C" void kernel_launch(void* const* d_in, const int* in_sizes, int n_in,
                              void* d_out, int out_size, void* d_ws, size_t ws_size,
                              hipStream_t stream) {
    const float* x        = (const float*)d_in[0];
    const float* skip     = (const float*)d_in[1];
    const float* convT_w  = (const float*)d_in[4];
    const float* convT_b  = (const float*)d_in[5];
    const float* fuse_w   = (const float*)d_in[6];
    const float* fuse_b   = (const float*)d_in[7];
    const float* norm_w   = (const float*)d_in[8];
    const float* norm_b   = (const float*)d_in[9];
    const float* in_proj  = (const float*)d_in[10];
    const float* conv_w   = (const float*)d_in[11];
    const float* conv_b   = (const float*)d_in[12];
    const float* x_proj   = (const float*)d_in[13];
    const float* dt_projw = (const float*)d_in[14];
    const float* dt_projb = (const float*)d_in[15];
    const float* A_log    = (const float*)d_in[16];
    const float* D_skip   = (const float*)d_in[17];
    const float* out_proj = (const float*)d_in[18];
    float* out = (float*)d_out;

    float* w = (float*)d_ws;
    size_t off = 0;
    auto alloc = [&](size_t n) { float* p = w + off; off += n; return p; };
    float* hT      = alloc((size_t)B_ * L_ * F_);       // 514048 (dead after fuse5)
    float* W2p     = alloc(524288);                     // dead after convt5
    float* fwTp    = alloc(32768);                      // dead after fuse5
    float* ipTp    = alloc(262144);
    float* opTp    = alloc(262144);
    float* xpTp    = alloc(65536);
    float* xs      = alloc(2 * RL_ * F_);
    float* cur     = alloc(2 * RL_ * F_);               // only dsum-alias now
    float* res1    = alloc(2 * RL_ * F_);
    float* xzz     = alloc(2 * RL_ * DI_);              // z-half only
    float* xc      = alloc(2 * RL_ * DI_);
    float* dl      = alloc(2 * RL_ * DI_);
    float* bcm     = alloc(2 * RL_ * 32);
    float* yb      = alloc(2 * RL_ * DI_);
    // scan chunk summaries alias dead regions:
    //   hp   (2*2*64*4096 = 1048576) -> hT+W2p+fwTp (1071104 floats, dead by scan)
    //   dsum (2*2*64*256  =   65536) -> cur (never otherwise written now)
    float* hp   = hT;
    float* dsum = cur;
    (void)ws_size; (void)in_sizes; (void)n_in; (void)out_size;

    prep_k<<<(PREP_N + 255) / 256, 256, 0, stream>>>(convT_w, fuse_w, in_proj, out_proj,
                                                     x_proj, W2p, fwTp, ipTp, opTp, xpTp);
    convt5_k<<<dim3(63, 2, 2), 256, 0, stream>>>(x, W2p, convT_b, hT);
    fuse5_k<<<dim3(251, 2), 256, 0, stream>>>(skip, hT, fwTp, fuse_b, xs);

    // Block 0 (resid = xs) -> res1
    lndw_k<<<dim3(502, 2), 256, 0, stream>>>(xs, norm_w, norm_b, ipTp,
                                             conv_w, conv_b, xpTp,
                                             dt_projw, dt_projb,
                                             xc, xzz, bcm, dl, 0);
    scanA_k<<<dim3(32, NC_, 2), 256, 0, stream>>>(dl, xc, bcm, A_log, D_skip,
                                                  yb, hp, dsum, 0);
    scanB_k<<<dim3(32, B_, 2), 256, 0, stream>>>(hp, dsum, A_log, 0);
    gateC_k<<<dim3(502, 2), 256, 0, stream>>>(yb, xzz, dl, bcm, A_log, hp,
                                              opTp, xs, res1, 0);

    // Block 1 (resid = res1) -> out (fwd + flipped bwd, fused)
    lndw_k<<<dim3(502, 2), 256, 0, stream>>>(res1, norm_w, norm_b, ipTp,
                                             conv_w, conv_b, xpTp,
                                             dt_projw, dt_projb,
                                             xc, xzz, bcm, dl, 1);
    scanA_k<<<dim3(32, NC_, 2), 256, 0, stream>>>(dl, xc, bcm, A_log, D_skip,
                                                  yb, hp, dsum, 1);
    scanB_k<<<dim3(32, B_, 2), 256, 0, stream>>>(hp, dsum, A_log, 1);
    gateC2_k<<<dim3(502), 256, 0, stream>>>(yb, xzz, dl, bcm, A_log, hp,
                                            opTp, res1, out);
}

// Round 13
// 387.772 us; speedup vs baseline: 1.2516x; 1.2516x over previous
//
#include <hip/hip_runtime.h>
#include <hip/hip_bf16.h>
#include <math.h>

// Problem constants
#define B_    2
#define FIN_  256
#define LIN_  250
#define F_    128      // F_OUT
#define K_    16       // KSIZE
#define ST_   8        // STRIDE
#define L_    2008     // L_OUT
#define DI_   256      // D_INNER
#define DS_   16       // D_STATE
#define RK_   8        // DT_RANK
#define CV_   4        // D_CONV
#define NBLK_ 2
#define NC_   64       // scan chunks (trailing chunk empty: identity summary)
#define CL_   32       // chunk length
#define RL_   ((size_t)B_ * L_)   // rows per direction = 4016 (= 502*8 exactly)

// fast-math activations: v_rcp_f32 / v_log_f32 instead of precise-div / log1pf
__device__ __forceinline__ float silu_f(float x) {
    return x * __builtin_amdgcn_rcpf(1.f + __expf(-x));
}
__device__ __forceinline__ float softplus_f(float x) {
    return (x > 20.f) ? x : __logf(1.f + __expf(x));
}
__device__ __forceinline__ float dot4(float4 a, float4 b) {
    return a.x * b.x + a.y * b.y + a.z * b.z + a.w * b.w;
}

// ---------------------------------------------------------------------------
// prep: packed transposed weights, each as [c/4][out][4] so a thread's 4-c
// weight bundle is ONE coalesced dwordx4.
// ---------------------------------------------------------------------------
#define PREP_N (524288 + 32768 + 262144 + 262144 + 65536)
__global__ void prep_k(const float* __restrict__ convT_w, const float* __restrict__ fuse_w,
                       const float* __restrict__ in_proj, const float* __restrict__ out_proj,
                       const float* __restrict__ x_proj,
                       float* __restrict__ W2p, float* __restrict__ fwTp,
                       float* __restrict__ ipTp, float* __restrict__ opTp,
                       float* __restrict__ xpTp) {
    size_t g = (size_t)blockIdx.x * 256 + threadIdx.x;
    if (g >= PREP_N) return;
    if (g < 524288) {
        int ccq = g >> 12, rr = g & 4095;
        int po = rr >> 2, i = rr & 3;
        int cc = ccq * 4 + i;
        int p = po >> 7, o = po & 127;
        int c = cc & 255, k = (cc < 256) ? p : p + 8;
        W2p[g] = convT_w[(size_t)c * 2048 + o * 16 + k];
        return;
    }
    g -= 524288;
    if (g < 32768) {
        int cq = g >> 9, rr = g & 511;
        int o = rr >> 2, i = rr & 3;
        fwTp[g] = fuse_w[(size_t)o * 256 + cq * 4 + i];
        return;
    }
    g -= 32768;
    if (g < 262144) {
        int db = g >> 16, r = g & 65535;
        int cq = r >> 11, rr = r & 2047;
        int e = rr >> 2, i = rr & 3;
        ipTp[g] = in_proj[(size_t)db * 65536 + e * 128 + cq * 4 + i];
        return;
    }
    g -= 262144;
    if (g < 262144) {
        int db = g >> 15, r = g & 32767;
        int cq = r >> 9, rr = r & 511;
        int o = rr >> 2, i = rr & 3;
        opTp[g] = out_proj[(size_t)db * 32768 + o * 256 + cq * 4 + i];
        return;
    }
    g -= 262144;
    {
        int db = g >> 14, r = g & 16383;
        int cq = r >> 8, rr = r & 255;
        int e = rr >> 2, i = rr & 3;
        xpTp[g] = (e < 40) ? x_proj[(size_t)db * 10240 + e * 256 + cq * 4 + i] : 0.f;
    }
}

// ---------------------------------------------------------------------------
// convT+silu GEMM, 2 outputs/thread. grid (63 jt of 4, 2 nt, B), block 256.
// ---------------------------------------------------------------------------
__global__ void __launch_bounds__(256) convt5_k(
        const float* __restrict__ x, const float* __restrict__ W2p,
        const float* __restrict__ bias, float* __restrict__ hT) {
    int j0 = blockIdx.x * 4, nt = blockIdx.y, b = blockIdx.z;
    int po = nt * 512 + threadIdx.x;
    int p = po >> 7, o = po & 127;

    __shared__ float xr[5][264];   // rows j0-1 .. j0+3

    for (int idx = threadIdx.x; idx < 5 * 256; idx += 256) {
        int i = idx >> 8, c = idx & 255;
        int j = j0 - 1 + i;
        xr[i][c] = (j >= 0 && j < LIN_) ? x[((size_t)b * FIN_ + c) * LIN_ + j] : 0.f;
    }
    __syncthreads();

    float acca[4] = {0.f, 0.f, 0.f, 0.f};
    float accb[4] = {0.f, 0.f, 0.f, 0.f};
    const float4* W4 = (const float4*)W2p;

    for (int ccq = 0; ccq < 64; ++ccq) {
        float4 wa1 = W4[(size_t)ccq * 1024 + po];
        float4 wb1 = W4[(size_t)ccq * 1024 + po + 256];
        float4 wa2 = W4[(size_t)(ccq + 64) * 1024 + po];
        float4 wb2 = W4[(size_t)(ccq + 64) * 1024 + po + 256];
        float4 xv[5];
        #pragma unroll
        for (int i = 0; i < 5; ++i) xv[i] = *(const float4*)&xr[i][ccq * 4];
        #pragma unroll
        for (int jj = 0; jj < 4; ++jj) {
            acca[jj] += dot4(xv[jj + 1], wa1) + dot4(xv[jj], wa2);
            accb[jj] += dot4(xv[jj + 1], wb1) + dot4(xv[jj], wb2);
        }
    }
    float bo = bias[o];
    #pragma unroll
    for (int jj = 0; jj < 4; ++jj) {
        int j = j0 + jj;
        if (j <= 250) {
            hT[((size_t)b * L_ + 8 * j + p) * F_ + o]     = silu_f(acca[jj] + bo);
            hT[((size_t)b * L_ + 8 * j + p + 2) * F_ + o] = silu_f(accb[jj] + bo);
        }
    }
}

// ---------------------------------------------------------------------------
// fuse = silu(fuse_w @ [skip; h] + b); 2 outs/thread; xs fwd + flipped bwd.
// grid (251 l-tiles of 8, B), block 256
// ---------------------------------------------------------------------------
__global__ void __launch_bounds__(256) fuse5_k(
        const float* __restrict__ skip, const float* __restrict__ hT,
        const float* __restrict__ fwTp, const float* __restrict__ fb,
        float* __restrict__ xs) {
    int l0 = blockIdx.x * 8, b = blockIdx.y;
    int tid = threadIdx.x;

    __shared__ float ss[8][264];

    for (int idx = tid; idx < 128 * 8; idx += 256) {   // skip part (c<128)
        int c = idx >> 3, ll = idx & 7;
        ss[ll][c] = skip[((size_t)b * F_ + c) * L_ + l0 + ll];
    }
    for (int idx = tid; idx < 8 * 128; idx += 256) {   // h part (c>=128)
        int ll = idx >> 7, c = idx & 127;
        ss[ll][128 + c] = hT[((size_t)b * L_ + l0 + ll) * F_ + c];
    }
    __syncthreads();

    int o2 = tid & 63, rg = tid >> 6;
    float acca[2] = {0.f, 0.f}, accb[2] = {0.f, 0.f};
    const float4* W4 = (const float4*)fwTp;

    for (int cq = 0; cq < 64; ++cq) {
        float4 wa = W4[cq * 128 + o2];
        float4 wb = W4[cq * 128 + o2 + 64];
        #pragma unroll
        for (int rr = 0; rr < 2; ++rr) {
            float4 s = *(const float4*)&ss[rg * 2 + rr][cq * 4];
            acca[rr] += dot4(s, wa);
            accb[rr] += dot4(s, wb);
        }
    }
    float ba = fb[o2], bb = fb[o2 + 64];
    #pragma unroll
    for (int rr = 0; rr < 2; ++rr) {
        int l = l0 + rg * 2 + rr;
        float va = silu_f(acca[rr] + ba);
        float vb = silu_f(accb[rr] + bb);
        size_t rf = ((size_t)b * L_ + l) * F_;
        size_t rb = (RL_ + (size_t)b * L_ + (L_ - 1 - l)) * F_;
        xs[rf + o2] = va;       xs[rf + o2 + 64] = vb;
        xs[rb + o2] = va;       xs[rb + o2 + 64] = vb;
    }
}

// ---------------------------------------------------------------------------
// lndw: rows-tile 8. LN(11 rows w/ halo) -> in_proj BOTH halves in ONE loop
// (each us read feeds 2 outputs) -> depthwise conv in regs -> silu -> XC+xcs;
// z -> XZz; then x_proj(40)+dt_proj(256)+softplus. grid (502, 2), block 256.
// [r10 structure; only the activation intrinsics changed.]
// ---------------------------------------------------------------------------
__global__ void __launch_bounds__(256) lndw_k(
        const float* __restrict__ X, const float* __restrict__ nw,
        const float* __restrict__ nb_, const float* __restrict__ ipTp,
        const float* __restrict__ cw, const float* __restrict__ cb,
        const float* __restrict__ xpTp, const float* __restrict__ dtw,
        const float* __restrict__ dtb,
        float* __restrict__ XC, float* __restrict__ XZz,
        float* __restrict__ BCM, float* __restrict__ DELTA, int blk) {
    int rt = blockIdx.x, d = blockIdx.y;
    size_t rbase = (size_t)rt * 8;
    int tid = threadIdx.x, lane = tid & 63, wid = tid >> 6;
    int db = d * NBLK_ + blk;
    size_t dRL = (size_t)d * RL_;

    __shared__ float us[11][132];
    __shared__ float xcs[8][264];
    __shared__ float dts[8][8];

    // LN for staged rows rbase-3 .. rbase+7
    int wi0 = db * F_;
    for (int r = wid; r < 11; r += 4) {
        long grow = (long)rbase - 3 + r;
        float2 v = make_float2(0.f, 0.f);
        if (grow >= 0)
            v = *(const float2*)(X + (dRL + (size_t)grow) * F_ + lane * 2);
        float s1 = v.x + v.y, s2 = v.x * v.x + v.y * v.y;
        for (int off = 32; off; off >>= 1) {
            s1 += __shfl_xor(s1, off);
            s2 += __shfl_xor(s2, off);
        }
        float mu = s1 * (1.f / F_);
        float var = s2 * (1.f / F_) - mu * mu;
        float rstd = rsqrtf(var + 1e-5f);
        int c2 = lane * 2;
        us[r][c2]     = (v.x - mu) * rstd * nw[wi0 + c2]     + nb_[wi0 + c2];
        us[r][c2 + 1] = (v.y - mu) * rstd * nw[wi0 + c2 + 1] + nb_[wi0 + c2 + 1];
    }
    __syncthreads();

    int o = tid;   // channel index, 0..255
    const float4* W4 = (const float4*)(ipTp + (size_t)db * 65536);

    // in_proj x-half (11 rows) AND z-half (8 rows) sharing each us read
    float accx[11], accz[8];
    #pragma unroll
    for (int i = 0; i < 11; ++i) accx[i] = 0.f;
    #pragma unroll
    for (int i = 0; i < 8; ++i) accz[i] = 0.f;
    for (int cq = 0; cq < 32; ++cq) {
        float4 wx = W4[cq * 512 + o];
        float4 wz = W4[cq * 512 + 256 + o];
        #pragma unroll
        for (int r = 0; r < 11; ++r) {
            float4 u = *(const float4*)&us[r][cq * 4];
            accx[r] += dot4(u, wx);
            if (r >= 3) accz[r - 3] += dot4(u, wz);
        }
    }

    // depthwise conv + silu, in registers (thread owns channel o)
    {
        int wi = db * DI_ + o;
        float cw0 = cw[(size_t)wi * CV_ + 0], cw1 = cw[(size_t)wi * CV_ + 1];
        float cw2 = cw[(size_t)wi * CV_ + 2], cw3 = cw[(size_t)wi * CV_ + 3];
        float bias = cb[wi];
        #pragma unroll
        for (int r8 = 0; r8 < 8; ++r8) {
            size_t row = rbase + r8;
            int b_r = (row >= L_) ? 1 : 0;
            int l_r = (int)row - b_r * L_;
            int s = r8 + 3;
            float a = bias + accx[s] * cw3;
            if (l_r - 1 >= 0) a += accx[s - 1] * cw2;
            if (l_r - 2 >= 0) a += accx[s - 2] * cw1;
            if (l_r - 3 >= 0) a += accx[s - 3] * cw0;
            float v = silu_f(a);
            xcs[r8][o] = v;
            XC[(dRL + row) * DI_ + o] = v;
            XZz[(dRL + row) * DI_ + o] = accz[r8];
        }
    }
    __syncthreads();

    // x_proj: e = tid&63 (e<40 active), rg = tid>>6 covers 2 rows each
    {
        int e = tid & 63, rg = tid >> 6;
        float acc2[2] = {0.f, 0.f};
        const float4* Wx = (const float4*)(xpTp + (size_t)db * 16384);
        for (int cq = 0; cq < 64; ++cq) {
            float4 w = Wx[cq * 64 + e];
            #pragma unroll
            for (int rr = 0; rr < 2; ++rr)
                acc2[rr] += dot4(*(const float4*)&xcs[rg * 2 + rr][cq * 4], w);
        }
        if (e < RK_) {
            #pragma unroll
            for (int rr = 0; rr < 2; ++rr) dts[rg * 2 + rr][e] = acc2[rr];
        } else if (e < RK_ + 2 * DS_) {
            #pragma unroll
            for (int rr = 0; rr < 2; ++rr) {
                size_t row = rbase + rg * 2 + rr;
                BCM[(dRL + row) * 32 + (e - RK_)] = acc2[rr];
            }
        }
    }
    __syncthreads();

    // dt_proj + softplus
    {
        int wi = db * DI_ + o;
        float dwv[RK_];
        #pragma unroll
        for (int k = 0; k < RK_; ++k) dwv[k] = dtw[(size_t)wi * RK_ + k];
        float bias = dtb[wi];
        #pragma unroll
        for (int rr = 0; rr < 8; ++rr) {
            size_t row = rbase + rr;
            float a = bias;
            #pragma unroll
            for (int k = 0; k < RK_; ++k) a += dts[rr][k] * dwv[k];
            DELTA[(dRL + row) * DI_ + o] = softplus_f(a);
        }
    }
}

// ---------------------------------------------------------------------------
// scanA: LDS-staged chunk-local scan (CL=32) — r10-proven structure.
// Emits local y (with D*u folded), cum(dt) (overwrites DELTA), hpart, dtsum.
// grid (32 chgrp, NC_, 2), block 256 = 16 chl x 16 n
// ---------------------------------------------------------------------------
__global__ void __launch_bounds__(256) scanA_k(
        float* __restrict__ DELTA, const float* __restrict__ XC,
        const float* __restrict__ BCM, const float* __restrict__ A_log,
        const float* __restrict__ Dsk,
        float* __restrict__ Y, float* __restrict__ hpart,
        float* __restrict__ dsum, int blk) {
    int d = blockIdx.z, cnk = blockIdx.y;
    int chunit0 = blockIdx.x * 16;
    int chl = threadIdx.x >> 4, n = threadIdx.x & 15;
    int b = chunit0 >> 8, ch0 = chunit0 & 255;
    int ch = ch0 + chl;
    int t0 = cnk * CL_;
    int nt = L_ - t0; if (nt > CL_) nt = CL_;   // may be <= 0 (empty chunk)

    __shared__ float dt_s[CL_][16];
    __shared__ float u_s[CL_][16];
    __shared__ float bc_s[CL_][32];

    size_t rowbase = (size_t)d * RL_ + (size_t)b * L_ + t0;
    for (int idx = threadIdx.x; idx < CL_ * 16; idx += 256) {
        int t = idx >> 4, c = idx & 15;
        float dv = 0.f, uv = 0.f;
        if (t < nt) {
            dv = DELTA[(rowbase + t) * DI_ + ch0 + c];
            uv = XC[(rowbase + t) * DI_ + ch0 + c];
        }
        dt_s[t][c] = dv; u_s[t][c] = uv;
    }
    for (int idx = threadIdx.x; idx < CL_ * 32; idx += 256) {
        int t = idx >> 5, m = idx & 31;
        bc_s[t][m] = (t < nt) ? BCM[(rowbase + t) * 32 + m] : 0.f;
    }
    __syncthreads();

    int db = d * NBLK_ + blk;
    float A = -__expf(A_log[((size_t)db * DI_ + ch) * DS_ + n]);
    float Dch = Dsk[(size_t)db * DI_ + ch];
    float h = 0.f, cum = 0.f;
    for (int t = 0; t < nt; ++t) {
        float dt = dt_s[t][chl];
        float u  = u_s[t][chl];
        float Bt = bc_s[t][n];
        float Ct = bc_s[t][16 + n];
        cum += dt;
        h = __expf(dt * A) * h + dt * u * Bt;
        float yp = h * Ct;
        yp += __shfl_xor(yp, 1);
        yp += __shfl_xor(yp, 2);
        yp += __shfl_xor(yp, 4);
        yp += __shfl_xor(yp, 8);
        if (n == 0) {
            Y[(rowbase + t) * DI_ + ch] = yp + Dch * u;   // D-skip folded in
            DELTA[(rowbase + t) * DI_ + ch] = cum;        // inclusive prefix of dt
        }
    }
    size_t cb = (size_t)(d * B_ + b) * NC_ + cnk;
    hpart[cb * (DI_ * DS_) + ch * DS_ + n] = h;
    if (n == 0) dsum[cb * DI_ + ch] = cum;
}

// ---------------------------------------------------------------------------
// scanB: cross-chunk scan of summaries, LDS-staged. In-place on hpart.
// grid (32 chgrp of 8 ch, B, 2 dirs), block 256
// ---------------------------------------------------------------------------
__global__ void __launch_bounds__(256) scanB_k(
        float* __restrict__ hpart, const float* __restrict__ dsum,
        const float* __restrict__ A_log, int blk) {
    int chg = blockIdx.x, b = blockIdx.y, d = blockIdx.z;
    int ch0 = chg * 8;
    __shared__ float hs[NC_][8][16];   // 32 KB
    __shared__ float ds_s[NC_][8];     // 2 KB
    size_t cb0 = (size_t)(d * B_ + b) * NC_;

    for (int idx = threadIdx.x; idx < NC_ * 128; idx += 256) {
        int c = idx >> 7, r = idx & 127;
        hs[c][r >> 4][r & 15] =
            hpart[(cb0 + c) * (DI_ * DS_) + (size_t)(ch0 + (r >> 4)) * DS_ + (r & 15)];
    }
    for (int idx = threadIdx.x; idx < NC_ * 8; idx += 256) {
        int c = idx >> 3, r = idx & 7;
        ds_s[c][r] = dsum[(cb0 + c) * DI_ + ch0 + r];
    }
    __syncthreads();

    if (threadIdx.x < 128) {
        int chl = threadIdx.x >> 4, n = threadIdx.x & 15;
        float A = -__expf(A_log[((size_t)(d * NBLK_ + blk) * DI_ + ch0 + chl) * DS_ + n]);
        float h = 0.f;
        for (int c = 0; c < NC_; ++c) {
            float hc = hs[c][chl][n];
            hs[c][chl][n] = h;               // carry-in for chunk c
            h = __expf(A * ds_s[c][chl]) * h + hc;
        }
    }
    __syncthreads();

    for (int idx = threadIdx.x; idx < NC_ * 128; idx += 256) {
        int c = idx >> 7, r = idx & 127;
        hpart[(cb0 + c) * (DI_ * DS_) + (size_t)(ch0 + (r >> 4)) * DS_ + (r & 15)] =
            hs[c][r >> 4][r & 15];
    }
}

// ---------------------------------------------------------------------------
// gateC: correction + gate + out_proj GEMM (+ residual), rows-tile 8.
// (blk0 path — produces res1.) grid (502, 2), block 256.
// ---------------------------------------------------------------------------
__global__ void __launch_bounds__(256) gateC_k(
        const float* __restrict__ Y, const float* __restrict__ XZz,
        const float* __restrict__ DELTA /*=cum*/, const float* __restrict__ BCM,
        const float* __restrict__ A_log, const float* __restrict__ hcarry,
        const float* __restrict__ opTp, const float* __restrict__ resid_in,
        float* __restrict__ outp, int blk) {
    int rt = blockIdx.x, d = blockIdx.y;
    int tid = threadIdx.x;
    size_t rbase = (size_t)rt * 8;
    int db = d * NBLK_ + blk;
    size_t dRL = (size_t)d * RL_;

    __shared__ float yg[8][264];
    __shared__ float Cs[8][16];

    if (tid < 128) {
        int r = tid >> 4, n = tid & 15;
        Cs[r][n] = BCM[(dRL + rbase + r) * 32 + 16 + n];
    }
    __syncthreads();

    {
        int c = tid;   // channel
        float An[16];
        const float* Ab = A_log + ((size_t)db * DI_ + c) * DS_;
        #pragma unroll
        for (int n = 0; n < 16; ++n) An[n] = -__expf(Ab[n]);

        int b0 = (rbase >= L_) ? 1 : 0;
        int l0 = (int)rbase - b0 * L_;
        int ck0 = l0 >> 5;
        const float* hp0 = hcarry + ((size_t)(d * B_ + b0) * NC_ + ck0) * (DI_ * DS_) + (size_t)c * DS_;
        float K0[16];
        #pragma unroll
        for (int q = 0; q < 4; ++q) {
            float4 v0 = *(const float4*)(hp0 + q * 4);
            K0[4*q] = v0.x; K0[4*q+1] = v0.y; K0[4*q+2] = v0.z; K0[4*q+3] = v0.w;
        }

        #pragma unroll
        for (int r = 0; r < 8; ++r) {
            size_t ri = dRL + rbase + r;
            float cum = DELTA[ri * DI_ + c];
            float corr = 0.f;
            #pragma unroll
            for (int n = 0; n < 16; ++n)
                corr += Cs[r][n] * K0[n] * __expf(An[n] * cum);
            float yv = Y[ri * DI_ + c] + corr;
            float z  = XZz[ri * DI_ + c];
            yg[r][c] = yv * silu_f(z);
        }
    }
    __syncthreads();

    int o2 = tid & 63, rg = tid >> 6;
    float acca[2] = {0.f, 0.f};
    float accb[2] = {0.f, 0.f};
    const float4* W4 = (const float4*)(opTp + (size_t)db * 32768);

    for (int cq = 0; cq < 64; ++cq) {
        float4 wa = W4[cq * 128 + o2];
        float4 wb = W4[cq * 128 + o2 + 64];
        #pragma unroll
        for (int rr = 0; rr < 2; ++rr) {
            float4 u = *(const float4*)&yg[rg * 2 + rr][cq * 4];
            acca[rr] += dot4(u, wa);
            accb[rr] += dot4(u, wb);
        }
    }
    #pragma unroll
    for (int rr = 0; rr < 2; ++rr) {
        size_t ri = dRL + rbase + rg * 2 + rr;
        float va = acca[rr] + resid_in[ri * F_ + o2];
        float vb = accb[rr] + resid_in[ri * F_ + o2 + 64];
        outp[ri * F_ + o2]      = va;
        outp[ri * F_ + o2 + 64] = vb;
    }
}

// ---------------------------------------------------------------------------
// gateC2: blk1 final stage. One block handles the fwd tile (dir0, rows l0..)
// AND the matching flipped bwd tile (dir1, rows L-8-l0..), sums both (+res1)
// and writes out[b,o,l] directly. grid (502), block 256.
// ---------------------------------------------------------------------------
__global__ void __launch_bounds__(256) gateC2_k(
        const float* __restrict__ Y, const float* __restrict__ XZz,
        const float* __restrict__ DELTA /*=cum*/, const float* __restrict__ BCM,
        const float* __restrict__ A_log, const float* __restrict__ hcarry,
        const float* __restrict__ opTp, const float* __restrict__ res1,
        float* __restrict__ out) {
    int rt = blockIdx.x;                 // 0..501
    int b = rt / 251, l0 = (rt % 251) * 8;
    int tid = threadIdx.x;

    __shared__ float yg[8][264];
    __shared__ float og[8][132];
    __shared__ float Cs[2][8][16];

    {
        int dd = tid >> 7, r = (tid >> 4) & 7, n = tid & 15;
        int lb = dd ? (L_ - 8 - l0) : l0;
        size_t row = (size_t)dd * RL_ + (size_t)b * L_ + lb + r;
        Cs[dd][r][n] = BCM[row * 32 + 16 + n];
    }
    __syncthreads();

    for (int dd = 0; dd < 2; ++dd) {
        int lb = dd ? (L_ - 8 - l0) : l0;
        size_t rowbase = (size_t)dd * RL_ + (size_t)b * L_ + lb;
        int db = dd * NBLK_ + 1;

        {
            int c = tid;   // channel
            float An[16];
            const float* Ab = A_log + ((size_t)db * DI_ + c) * DS_;
            #pragma unroll
            for (int n = 0; n < 16; ++n) An[n] = -__expf(Ab[n]);

            int ck0 = lb >> 5;   // 8-aligned tile is chunk-contained
            const float* hp0 = hcarry + ((size_t)(dd * B_ + b) * NC_ + ck0) * (DI_ * DS_) + (size_t)c * DS_;
            float K0[16];
            #pragma unroll
            for (int q = 0; q < 4; ++q) {
                float4 v0 = *(const float4*)(hp0 + q * 4);
                K0[4*q] = v0.x; K0[4*q+1] = v0.y; K0[4*q+2] = v0.z; K0[4*q+3] = v0.w;
            }

            #pragma unroll
            for (int r = 0; r < 8; ++r) {
                size_t ri = rowbase + r;
                float cum = DELTA[ri * DI_ + c];
                float corr = 0.f;
                #pragma unroll
                for (int n = 0; n < 16; ++n)
                    corr += Cs[dd][r][n] * K0[n] * __expf(An[n] * cum);
                float yv = Y[ri * DI_ + c] + corr;
                float z  = XZz[ri * DI_ + c];
                yg[r][c] = yv * silu_f(z);
            }
        }
        __syncthreads();

        int o2 = tid & 63, rg = tid >> 6;
        float acca[2] = {0.f, 0.f};
        float accb[2] = {0.f, 0.f};
        const float4* W4 = (const float4*)(opTp + (size_t)db * 32768);

        for (int cq = 0; cq < 64; ++cq) {
            float4 wa = W4[cq * 128 + o2];
            float4 wb = W4[cq * 128 + o2 + 64];
            #pragma unroll
            for (int rr = 0; rr < 2; ++rr) {
                float4 u = *(const float4*)&yg[rg * 2 + rr][cq * 4];
                acca[rr] += dot4(u, wa);
                accb[rr] += dot4(u, wb);
            }
        }
        #pragma unroll
        for (int rr = 0; rr < 2; ++rr) {
            int ll = rg * 2 + rr;
            size_t ri = rowbase + ll;
            float va = acca[rr] + res1[ri * F_ + o2];
            float vb = accb[rr] + res1[ri * F_ + o2 + 64];
            if (dd == 0) {
                og[ll][o2]      = va;
                og[ll][o2 + 64] = vb;
            } else {
                og[7 - ll][o2]      += va;    // flip: out l = l0 + 7 - r
                og[7 - ll][o2 + 64] += vb;
            }
        }
        __syncthreads();   // protect yg reuse / og completion
    }

    for (int idx = tid; idx < 1024; idx += 256) {
        int o = idx >> 3, ll = idx & 7;
        out[((size_t)b * F_ + o) * L_ + l0 + ll] = og[ll][o];
    }
}

// ---------------------------------------------------------------------------
extern "C" void kernel_launch(void* const* d_in, const int* in_sizes, int n_in,
                              void* d_out, int out_size, void* d_ws, size_t ws_size,
                              hipStream_t stream) {
    const float* x        = (const float*)d_in[0];
    const float* skip     = (const float*)d_in[1];
    const float* convT_w  = (const float*)d_in[4];
    const float* convT_b  = (const float*)d_in[5];
    const float* fuse_w   = (const float*)d_in[6];
    const float* fuse_b   = (const float*)d_in[7];
    const float* norm_w   = (const float*)d_in[8];
    const float* norm_b   = (const float*)d_in[9];
    const float* in_proj  = (const float*)d_in[10];
    const float* conv_w   = (const float*)d_in[11];
    const float* conv_b   = (const float*)d_in[12];
    const float* x_proj   = (const float*)d_in[13];
    const float* dt_projw = (const float*)d_in[14];
    const float* dt_projb = (const float*)d_in[15];
    const float* A_log    = (const float*)d_in[16];
    const float* D_skip   = (const float*)d_in[17];
    const float* out_proj = (const float*)d_in[18];
    float* out = (float*)d_out;

    float* w = (float*)d_ws;
    size_t off = 0;
    auto alloc = [&](size_t n) { float* p = w + off; off += n; return p; };
    float* hT      = alloc((size_t)B_ * L_ * F_);       // 514048 (dead after fuse5)
    float* W2p     = alloc(524288);                     // dead after convt5
    float* fwTp    = alloc(32768);                      // dead after fuse5
    float* ipTp    = alloc(262144);
    float* opTp    = alloc(262144);
    float* xpTp    = alloc(65536);
    float* xs      = alloc(2 * RL_ * F_);
    float* cur     = alloc(2 * RL_ * F_);               // only dsum-alias now
    float* res1    = alloc(2 * RL_ * F_);
    float* xzz     = alloc(2 * RL_ * DI_);              // z-half only
    float* xc      = alloc(2 * RL_ * DI_);
    float* dl      = alloc(2 * RL_ * DI_);
    float* bcm     = alloc(2 * RL_ * 32);
    float* yb      = alloc(2 * RL_ * DI_);
    // scan chunk summaries alias dead regions:
    //   hp   (2*2*64*4096 = 1048576) -> hT+W2p+fwTp (1071104 floats, dead by scan)
    //   dsum (2*2*64*256  =   65536) -> cur (never otherwise written now)
    float* hp   = hT;
    float* dsum = cur;
    (void)ws_size; (void)in_sizes; (void)n_in; (void)out_size;

    prep_k<<<(PREP_N + 255) / 256, 256, 0, stream>>>(convT_w, fuse_w, in_proj, out_proj,
                                                     x_proj, W2p, fwTp, ipTp, opTp, xpTp);
    convt5_k<<<dim3(63, 2, 2), 256, 0, stream>>>(x, W2p, convT_b, hT);
    fuse5_k<<<dim3(251, 2), 256, 0, stream>>>(skip, hT, fwTp, fuse_b, xs);

    // Block 0 (resid = xs) -> res1
    lndw_k<<<dim3(502, 2), 256, 0, stream>>>(xs, norm_w, norm_b, ipTp,
                                             conv_w, conv_b, xpTp,
                                             dt_projw, dt_projb,
                                             xc, xzz, bcm, dl, 0);
    scanA_k<<<dim3(32, NC_, 2), 256, 0, stream>>>(dl, xc, bcm, A_log, D_skip,
                                                  yb, hp, dsum, 0);
    scanB_k<<<dim3(32, B_, 2), 256, 0, stream>>>(hp, dsum, A_log, 0);
    gateC_k<<<dim3(502, 2), 256, 0, stream>>>(yb, xzz, dl, bcm, A_log, hp,
                                              opTp, xs, res1, 0);

    // Block 1 (resid = res1) -> out (fwd + flipped bwd, fused)
    lndw_k<<<dim3(502, 2), 256, 0, stream>>>(res1, norm_w, norm_b, ipTp,
                                             conv_w, conv_b, xpTp,
                                             dt_projw, dt_projb,
                                             xc, xzz, bcm, dl, 1);
    scanA_k<<<dim3(32, NC_, 2), 256, 0, stream>>>(dl, xc, bcm, A_log, D_skip,
                                                  yb, hp, dsum, 1);
    scanB_k<<<dim3(32, B_, 2), 256, 0, stream>>>(hp, dsum, A_log, 1);
    gateC2_k<<<dim3(502), 256, 0, stream>>>(yb, xzz, dl, bcm, A_log, hp,
                                            opTp, res1, out);
}